// Round 8
// baseline (33.800 us; speedup 1.0000x reference)
//
#include <hip/hip_runtime.h>

#define NEG_SLOPE 0.01f

typedef _Float16 f16;
typedef _Float16 f16x4 __attribute__((ext_vector_type(4)));
typedef float    f32x4 __attribute__((ext_vector_type(4)));

__device__ __forceinline__ float leaky(float v) {
    // 0 < slope < 1  =>  leaky(v) == max(v, slope*v)
    return fmaxf(v, NEG_SLOPE * v);
}

// ---------------- Fully fused kernel ----------------
// One 256-thread block per (b,i). 4 waves split the 32 j-tiles (8 each).
// Lane (p=l&15, c4=(l>>4)*4) per tile:
//   pj/h1 from x directly:  s = xj0*Wc1_j0 + xj1*Wc1_j1 + piu   (f32, exact)
//   b1 = f16(leaky(s))                                          (one rounding)
//   d1 = Wc2^T(hi) x b1 + (Wc2^T(lo) x b1 + bc2)   (2 MFMAs, exact weights)
//   sig = sigmoid(A_param[i,j]) (0 on diagonal, computed in-loop)
//   accE[e] += sig * leaky(d1[e]);  vS += sig
// pp = accE.w3 + 0.25*b3*vS; butterfly(64); LDS reduce over the 4 waves.
// Wave 0 additionally computes the 64-wide node MLP for row (b,i).
__global__ __launch_bounds__(256) void fused_ode(
    const float* __restrict__ x,
    const float* __restrict__ Wn1, const float* __restrict__ bn1,
    const float* __restrict__ Wn2, const float* __restrict__ bn2,
    const float* __restrict__ Wn3, const float* __restrict__ bn3,
    const float* __restrict__ Wc1, const float* __restrict__ bc1,
    const float* __restrict__ Wc2, const float* __restrict__ bc2,
    const float* __restrict__ Wc3, const float* __restrict__ bc3,
    const float* __restrict__ A_param,
    float* __restrict__ out)
{
    __shared__ float sh[64];      // node-MLP h1 (wave 0 only; intra-wave use)
    __shared__ float sred[4];

    const int t  = threadIdx.x;
    const int l  = t & 63;            // lane in wave
    const int wv = t >> 6;            // wave 0..3
    const int p  = l & 15;            // pair slot within tile
    const int c4 = (l >> 4) << 2;     // channel base
    const int bi = blockIdx.x;        // b*512 + i
    const int b  = bi >> 9;
    const int i  = bi & 511;

    const float xi0 = x[bi * 2 + 0];
    const float xi1 = x[bi * 2 + 1];

    // ---- prologue: per-lane weight fragments (all tables tiny, L1-resident) ----
    f16x4 w2hi, w2lo;
    f32x4 c1;                          // C for MFMA: bc2[c4+e]
    float w3[4], wj0[4], wj1[4], piu[4];
    #pragma unroll
    for (int e = 0; e < 4; ++e) {
        const int c = c4 + e;
        const float w2 = Wc2[c * 16 + p];
        const f16 hw = (f16)w2;
        w2hi[e] = hw; w2lo[e] = (f16)(w2 - (float)hw);
        c1[e] = bc2[c];
        w3[e] = Wc3[c];
        wj0[e] = Wc1[c];
        wj1[e] = Wc1[16 + c];
        piu[e] = fmaf(xi0, Wc1[32 + c], fmaf(xi1, Wc1[48 + c], bc1[c]));
    }
    const float b3q = 0.25f * bc3[0];

    const float* xb = x + b * 1024;       // x[b][j][2]
    const float* Ar = A_param + i * 512;  // A_param[i][*]

    // ---- coupling: 8 tiles per wave ----
    float accE[4] = {0.0f, 0.0f, 0.0f, 0.0f};
    float vS = 0.0f;
    #pragma unroll
    for (int tt = 0; tt < 8; ++tt) {
        const int j = (wv * 8 + tt) * 16 + p;
        const float2 xj = *reinterpret_cast<const float2*>(xb + j * 2);

        f16x4 b1;
        #pragma unroll
        for (int e = 0; e < 4; ++e) {
            const float s = fmaf(xj.x, wj0[e], fmaf(xj.y, wj1[e], piu[e]));
            b1[e] = (f16)fmaxf(s, NEG_SLOPE * s);
        }

        f32x4 d1 = __builtin_amdgcn_mfma_f32_16x16x16f16(w2lo, b1, c1, 0, 0, 0);
        d1 = __builtin_amdgcn_mfma_f32_16x16x16f16(w2hi, b1, d1, 0, 0, 0);

        const float a = Ar[j];
        float sig = __fdividef(1.0f, 1.0f + __expf(-a));
        if (j == i) sig = 0.0f;       // sigmoid(0 - 1e5) == 0 in f32
        vS += sig;
        #pragma unroll
        for (int e = 0; e < 4; ++e)
            accE[e] = fmaf(fmaxf(d1[e], NEG_SLOPE * d1[e]), sig, accE[e]);
    }

    float pp = fmaf(accE[0], w3[0],
               fmaf(accE[1], w3[1],
               fmaf(accE[2], w3[2], accE[3] * w3[3])));
    pp = fmaf(b3q, vS, pp);            // 4-way lane duplication of sig -> x0.25

    // sum over 16 pairs x 4 channel groups within the wave
    #pragma unroll
    for (int off = 32; off > 0; off >>= 1)
        pp += __shfl_xor(pp, off, 64);
    if (l == 0) sred[wv] = pp;

    // ---- node MLP for this row, on wave 0 (intra-wave LDS, DS in-order) ----
    float node = 0.0f;
    if (wv == 0) {
        const float h1 = leaky(fmaf(xi0, Wn1[l], fmaf(xi1, Wn1[64 + l], bn1[l])));
        sh[l] = h1;
        float acc = bn2[l];
        #pragma unroll
        for (int c = 0; c < 64; ++c)
            acc = fmaf(sh[c], Wn2[c * 64 + l], acc);
        const float h2 = leaky(acc);
        float pn = h2 * Wn3[l];
        #pragma unroll
        for (int off = 32; off > 0; off >>= 1)
            pn += __shfl_xor(pn, off, 64);
        node = pn + bn3[0];
    }

    __syncthreads();
    if (t == 0) {
        out[bi * 2 + 0] = xi1;        // out0 = x[...,1]
        out[bi * 2 + 1] = node + sred[0] + sred[1] + sred[2] + sred[3];
    }
}

extern "C" void kernel_launch(void* const* d_in, const int* in_sizes, int n_in,
                              void* d_out, int out_size, void* d_ws, size_t ws_size,
                              hipStream_t stream) {
    const float* x       = (const float*)d_in[0];
    const float* Wn1     = (const float*)d_in[1];
    const float* bn1     = (const float*)d_in[2];
    const float* Wn2     = (const float*)d_in[3];
    const float* bn2     = (const float*)d_in[4];
    const float* Wn3     = (const float*)d_in[5];
    const float* bn3     = (const float*)d_in[6];
    const float* Wc1     = (const float*)d_in[7];
    const float* bc1     = (const float*)d_in[8];
    const float* Wc2     = (const float*)d_in[9];
    const float* bc2     = (const float*)d_in[10];
    const float* Wc3     = (const float*)d_in[11];
    const float* bc3     = (const float*)d_in[12];
    const float* A_param = (const float*)d_in[13];
    float* out = (float*)d_out;

    const int BN = 16 * 512;          // 8192 rows = one block each

    fused_ode<<<BN, 256, 0, stream>>>(x, Wn1, bn1, Wn2, bn2, Wn3, bn3,
                                      Wc1, bc1, Wc2, bc2, Wc3, bc3,
                                      A_param, out);
}

// Round 9
// 24.368 us; speedup vs baseline: 1.3871x; 1.3871x over previous
//
#include <hip/hip_runtime.h>

#define NEG_SLOPE 0.01f

typedef _Float16 f16;
typedef _Float16 f16x4 __attribute__((ext_vector_type(4)));
typedef float    f32x4 __attribute__((ext_vector_type(4)));

__device__ __forceinline__ float leaky(float v) {
    return fmaxf(v, NEG_SLOPE * v);
}

// ---------------- Fully fused, one kernel ----------------
// Block (256 thr) = 4 waves; wave wv owns i = blockIdx.x*4 + wv completely.
// Phase 1: all threads stage pj[512][16] (f16, XOR-swizzled) into LDS; each
//          wave computes its node-MLP row (intra-wave LDS, no barrier).
// Phase 2 (after one barrier): 8 super-tiles of 64 j's:
//          lane l computes sig_j for j=sup*64+l once (coalesced A load),
//          4 sub-tiles: sig via ds_bpermute; h1 = pk(pj4 + piu4, leaky);
//          d1 = Wc2^T(hi)xB + (Wc2^T(lo)xB + bc2)  (2 MFMAs, exact weights);
//          accE[e] += (0.505sig)*d1[e] + (0.495sig)*|d1[e]|   (leaky folded)
// Epilogue: pp = accE.w3 + bc3*vS + node_partial; one 64-lane butterfly.
__global__ __launch_bounds__(256) void fused_all(
    const float* __restrict__ x,
    const float* __restrict__ Wn1, const float* __restrict__ bn1,
    const float* __restrict__ Wn2, const float* __restrict__ bn2,
    const float* __restrict__ Wn3, const float* __restrict__ bn3,
    const float* __restrict__ Wc1, const float* __restrict__ bc1,
    const float* __restrict__ Wc2, const float* __restrict__ bc2,
    const float* __restrict__ Wc3, const float* __restrict__ bc3,
    const float* __restrict__ A_param,
    float* __restrict__ out)
{
    __shared__ unsigned char pjbuf[512 * 32];   // f16 [512][16], swizzled
    __shared__ float shn[4][64];                // node-MLP h1, per wave

    const int t  = threadIdx.x;
    const int l  = t & 63;
    const int wv = t >> 6;
    const int p  = l & 15;            // pair slot within 16-j tile
    const int g  = l >> 4;            // channel group (c4 = 4g)
    const int c4 = g << 2;
    const int bi = blockIdx.x * 4 + wv;   // b*512 + i
    const int b  = bi >> 9;
    const int i  = bi & 511;

    const float* xb = x + b * 1024;   // x[b][j][2]

    // ---- Phase 1a: stage pj (f16) into LDS; thread t covers j = t, t+256 ----
    #pragma unroll
    for (int jj = 0; jj < 2; ++jj) {
        const int j = t + jj * 256;
        const float2 xj = *reinterpret_cast<const float2*>(xb + j * 2);
        f16 v[16];
        #pragma unroll
        for (int c = 0; c < 16; ++c)
            v[c] = (f16)fmaf(xj.x, Wc1[c], xj.y * Wc1[16 + c]);
        const int sw = ((j >> 2) & 3) << 3;
        #pragma unroll
        for (int gg = 0; gg < 4; ++gg) {
            const int addr = j * 32 + ((gg << 3) ^ sw);
            *reinterpret_cast<f16x4*>(pjbuf + addr) =
                (f16x4){v[4*gg], v[4*gg+1], v[4*gg+2], v[4*gg+3]};
        }
    }

    const float xi0 = xb[i * 2 + 0];
    const float xi1 = xb[i * 2 + 1];

    // ---- Phase 1b: per-lane weight fragments + piu (f16) ----
    f16x4 w2lo, w2hi, piu4;
    f32x4 c1;
    float w3r[4];
    #pragma unroll
    for (int e = 0; e < 4; ++e) {
        const int c = c4 + e;
        const float w2 = Wc2[c * 16 + p];
        const f16 hw = (f16)w2;
        w2hi[e] = hw; w2lo[e] = (f16)(w2 - (float)hw);
        c1[e]  = bc2[c];
        w3r[e] = Wc3[c];
        piu4[e] = (f16)fmaf(xi0, Wc1[32 + c], fmaf(xi1, Wc1[48 + c], bc1[c]));
    }
    const f16x4 slope4 = {(f16)NEG_SLOPE, (f16)NEG_SLOPE, (f16)NEG_SLOPE, (f16)NEG_SLOPE};

    // ---- Phase 1c: node MLP for row (b,i) — intra-wave, DS in-order ----
    const float h1n = leaky(fmaf(xi0, Wn1[l], fmaf(xi1, Wn1[64 + l], bn1[l])));
    shn[wv][l] = h1n;
    float accn = bn2[l];
    #pragma unroll 8
    for (int c = 0; c < 64; ++c)
        accn = fmaf(shn[wv][c], Wn2[c * 64 + l], accn);
    const float pn = leaky(accn) * Wn3[l];   // per-lane node partial

    __syncthreads();   // pj staging complete

    // ---- Phase 2: 8 super-tiles x 4 tiles ----
    const float* Ar = A_param + i * 512;
    const int supd = i >> 6, land = i & 63;
    const int rbase = p * 32 + ((g << 3) ^ (((p >> 2) & 3) << 3));

    float accE0 = 0.f, accE1 = 0.f, accE2 = 0.f, accE3 = 0.f, vSl = 0.f;
    #pragma unroll 2
    for (int sup = 0; sup < 8; ++sup) {
        const float a = Ar[sup * 64 + l];
        float sg = __fdividef(1.0f, 1.0f + __expf(-a));
        if (sup == supd && l == land) sg = 0.0f;   // sigmoid(-1e5) == 0
        vSl += sg;
        const int sgbits = __float_as_int(sg);
        #pragma unroll
        for (int tt = 0; tt < 4; ++tt) {
            const float sigt = __int_as_float(
                __builtin_amdgcn_ds_bpermute((tt * 16 + p) * 4, sgbits));
            const f16x4 pj4 = *reinterpret_cast<const f16x4*>(
                pjbuf + rbase + (sup * 4 + tt) * 512);

            const f16x4 s4 = pj4 + piu4;
            const f16x4 b1 = __builtin_elementwise_max(s4, s4 * slope4);

            f32x4 d1 = __builtin_amdgcn_mfma_f32_16x16x16f16(w2lo, b1, c1, 0, 0, 0);
            d1 = __builtin_amdgcn_mfma_f32_16x16x16f16(w2hi, b1, d1, 0, 0, 0);

            const float sg0 = 0.505f * sigt;
            const float sg1 = 0.495f * sigt;
            accE0 = fmaf(sg0, d1[0], fmaf(sg1, fabsf(d1[0]), accE0));
            accE1 = fmaf(sg0, d1[1], fmaf(sg1, fabsf(d1[1]), accE1));
            accE2 = fmaf(sg0, d1[2], fmaf(sg1, fabsf(d1[2]), accE2));
            accE3 = fmaf(sg0, d1[3], fmaf(sg1, fabsf(d1[3]), accE3));
        }
    }

    // ---- Epilogue: fold node partial + bc3 term, single butterfly ----
    float pp = fmaf(accE0, w3r[0],
               fmaf(accE1, w3r[1],
               fmaf(accE2, w3r[2], accE3 * w3r[3])));
    pp = fmaf(bc3[0], vSl, pp) + pn;

    #pragma unroll
    for (int off = 32; off > 0; off >>= 1)
        pp += __shfl_xor(pp, off, 64);

    if (l == 0) {
        out[bi * 2 + 0] = xi1;                 // out0 = x[...,1]
        out[bi * 2 + 1] = pp + bn3[0];         // node bias added once
    }
}

extern "C" void kernel_launch(void* const* d_in, const int* in_sizes, int n_in,
                              void* d_out, int out_size, void* d_ws, size_t ws_size,
                              hipStream_t stream) {
    const float* x       = (const float*)d_in[0];
    const float* Wn1     = (const float*)d_in[1];
    const float* bn1     = (const float*)d_in[2];
    const float* Wn2     = (const float*)d_in[3];
    const float* bn2     = (const float*)d_in[4];
    const float* Wn3     = (const float*)d_in[5];
    const float* bn3     = (const float*)d_in[6];
    const float* Wc1     = (const float*)d_in[7];
    const float* bc1     = (const float*)d_in[8];
    const float* Wc2     = (const float*)d_in[9];
    const float* bc2     = (const float*)d_in[10];
    const float* Wc3     = (const float*)d_in[11];
    const float* bc3     = (const float*)d_in[12];
    const float* A_param = (const float*)d_in[13];
    float* out = (float*)d_out;

    const int BN = 16 * 512;          // 8192 rows; 4 per block

    fused_all<<<BN / 4, 256, 0, stream>>>(x, Wn1, bn1, Wn2, bn2, Wn3, bn3,
                                          Wc1, bc1, Wc2, bc2, Wc3, bc3,
                                          A_param, out);
}

// Round 10
// 21.917 us; speedup vs baseline: 1.5422x; 1.1118x over previous
//
#include <hip/hip_runtime.h>

#define NEG_SLOPE 0.01f

typedef _Float16 f16;
typedef _Float16 f16x4 __attribute__((ext_vector_type(4)));
typedef float    f32x4 __attribute__((ext_vector_type(4)));

__device__ __forceinline__ float leaky(float v) {
    return fmaxf(v, NEG_SLOPE * v);
}

// ---------------- Fully fused, one kernel, 2 rows per wave ----------------
// 1024 blocks x 256 thr. Block covers rows ia = blockIdx*8 .. +7 (same b).
// Wave wv owns rows (ia, ia+1), ia = blockIdx*8 + wv*2.
// Phase 1: stage pj[512][16] f16 (swizzled) in LDS (shared by all 8 rows);
//          node MLP for both rows (shared Wn2 loads, float2-packed h1);
//          sigmoid rows for both i's -> LDS float2 (intra-wave, no barrier).
// Phase 2: 32 subtiles: one shared pj ds_read feeds BOTH rows' MFMA pairs;
//          sig pair via one ds_read_b64; leaky folded as 0.505v+0.495|v|.
// Epilogue: two dots + two butterflies; lane 0 writes 4 outputs.
__global__ __launch_bounds__(256, 4) void fused_all2(
    const float* __restrict__ x,
    const float* __restrict__ Wn1, const float* __restrict__ bn1,
    const float* __restrict__ Wn2, const float* __restrict__ bn2,
    const float* __restrict__ Wn3, const float* __restrict__ bn3,
    const float* __restrict__ Wc1, const float* __restrict__ bc1,
    const float* __restrict__ Wc2, const float* __restrict__ bc2,
    const float* __restrict__ Wc3, const float* __restrict__ bc3,
    const float* __restrict__ A_param,
    float* __restrict__ out)
{
    __shared__ unsigned char pjbuf[512 * 32];   // f16 [512][16], swizzled
    __shared__ float2 shn[4][64];               // node h1 pairs, per wave
    __shared__ float2 sigbuf[4][512];           // sigmoid pairs, per wave

    const int t  = threadIdx.x;
    const int l  = t & 63;
    const int wv = t >> 6;
    const int p  = l & 15;            // pair slot within 16-j tile
    const int g  = l >> 4;            // channel group
    const int c4 = g << 2;
    const int ia = blockIdx.x * 8 + wv * 2;   // even global row (b*512 + i0)
    const int ib = ia + 1;
    const int bb = ia >> 9;
    const int i0 = ia & 511, i1 = i0 + 1;

    const float* xb = x + bb * 1024;  // x[b][j][2]

    // ---- Phase 1a: stage pj (f16) into LDS; thread t covers j = t, t+256 ----
    #pragma unroll
    for (int jj = 0; jj < 2; ++jj) {
        const int j = t + jj * 256;
        const float2 xj = *reinterpret_cast<const float2*>(xb + j * 2);
        f16 v[16];
        #pragma unroll
        for (int c = 0; c < 16; ++c)
            v[c] = (f16)fmaf(xj.x, Wc1[c], xj.y * Wc1[16 + c]);
        const int sw = ((j >> 2) & 3) << 3;
        #pragma unroll
        for (int gg = 0; gg < 4; ++gg) {
            const int addr = j * 32 + ((gg << 3) ^ sw);
            *reinterpret_cast<f16x4*>(pjbuf + addr) =
                (f16x4){v[4*gg], v[4*gg+1], v[4*gg+2], v[4*gg+3]};
        }
    }

    const float2 xia = *reinterpret_cast<const float2*>(xb + i0 * 2);
    const float2 xib = *reinterpret_cast<const float2*>(xb + i1 * 2);

    // ---- Phase 1b: weight fragments (row-independent) + per-row piu ----
    f16x4 w2lo, w2hi, piua, piub;
    f32x4 c1;
    float w3r[4];
    #pragma unroll
    for (int e = 0; e < 4; ++e) {
        const int c = c4 + e;
        const float w2 = Wc2[c * 16 + p];
        const f16 hw = (f16)w2;
        w2hi[e] = hw; w2lo[e] = (f16)(w2 - (float)hw);
        c1[e]  = bc2[c];
        w3r[e] = Wc3[c];
        const float wi0 = Wc1[32 + c], wi1 = Wc1[48 + c], bce = bc1[c];
        piua[e] = (f16)fmaf(xia.x, wi0, fmaf(xia.y, wi1, bce));
        piub[e] = (f16)fmaf(xib.x, wi0, fmaf(xib.y, wi1, bce));
    }
    const f16x4 slope4 = {(f16)NEG_SLOPE, (f16)NEG_SLOPE, (f16)NEG_SLOPE, (f16)NEG_SLOPE};

    // ---- Phase 1c: node MLP for both rows (shared Wn2 loads) ----
    const float h1a = leaky(fmaf(xia.x, Wn1[l], fmaf(xia.y, Wn1[64 + l], bn1[l])));
    const float h1b = leaky(fmaf(xib.x, Wn1[l], fmaf(xib.y, Wn1[64 + l], bn1[l])));
    shn[wv][l] = make_float2(h1a, h1b);
    float na = bn2[l], nb = bn2[l];
    #pragma unroll 8
    for (int c = 0; c < 64; ++c) {
        const float w = Wn2[c * 64 + l];
        const float2 hh = shn[wv][c];
        na = fmaf(hh.x, w, na);
        nb = fmaf(hh.y, w, nb);
    }
    const float pna = leaky(na) * Wn3[l];
    const float pnb = leaky(nb) * Wn3[l];

    // ---- Phase 1d: sigmoid rows for both i's -> LDS (intra-wave use) ----
    float vsa = 0.f, vsb = 0.f;
    const float* Ara = A_param + i0 * 512;
    const float* Arb = Ara + 512;
    #pragma unroll
    for (int s = 0; s < 8; ++s) {
        const int j = s * 64 + l;
        float sa = __fdividef(1.f, 1.f + __expf(-Ara[j]));
        float sb = __fdividef(1.f, 1.f + __expf(-Arb[j]));
        if (j == i0) sa = 0.f;        // sigmoid(0 - 1e5) == 0 in f32
        if (j == i1) sb = 0.f;
        vsa += sa; vsb += sb;
        sigbuf[wv][j] = make_float2(sa, sb);
    }

    __syncthreads();   // pjbuf staging complete (shn/sigbuf are intra-wave)

    // ---- Phase 2: 32 subtiles, both rows share the pj read ----
    const int rbase = p * 32 + ((g << 3) ^ (((p >> 2) & 3) << 3));
    float aA0=0.f,aA1=0.f,aA2=0.f,aA3=0.f;
    float aB0=0.f,aB1=0.f,aB2=0.f,aB3=0.f;
    #pragma unroll 2
    for (int T = 0; T < 32; ++T) {
        const f16x4 pj4 = *reinterpret_cast<const f16x4*>(pjbuf + rbase + T * 512);
        const float2 sg2 = sigbuf[wv][T * 16 + p];

        const f16x4 s4a = pj4 + piua;
        const f16x4 b1a = __builtin_elementwise_max(s4a, s4a * slope4);
        f32x4 d1a = __builtin_amdgcn_mfma_f32_16x16x16f16(w2lo, b1a, c1, 0, 0, 0);
        d1a = __builtin_amdgcn_mfma_f32_16x16x16f16(w2hi, b1a, d1a, 0, 0, 0);

        const f16x4 s4b = pj4 + piub;
        const f16x4 b1b = __builtin_elementwise_max(s4b, s4b * slope4);
        f32x4 d1b = __builtin_amdgcn_mfma_f32_16x16x16f16(w2lo, b1b, c1, 0, 0, 0);
        d1b = __builtin_amdgcn_mfma_f32_16x16x16f16(w2hi, b1b, d1b, 0, 0, 0);

        const float sa0 = 0.505f * sg2.x, sa1 = 0.495f * sg2.x;
        aA0 = fmaf(sa0, d1a[0], fmaf(sa1, fabsf(d1a[0]), aA0));
        aA1 = fmaf(sa0, d1a[1], fmaf(sa1, fabsf(d1a[1]), aA1));
        aA2 = fmaf(sa0, d1a[2], fmaf(sa1, fabsf(d1a[2]), aA2));
        aA3 = fmaf(sa0, d1a[3], fmaf(sa1, fabsf(d1a[3]), aA3));

        const float sb0 = 0.505f * sg2.y, sb1 = 0.495f * sg2.y;
        aB0 = fmaf(sb0, d1b[0], fmaf(sb1, fabsf(d1b[0]), aB0));
        aB1 = fmaf(sb0, d1b[1], fmaf(sb1, fabsf(d1b[1]), aB1));
        aB2 = fmaf(sb0, d1b[2], fmaf(sb1, fabsf(d1b[2]), aB2));
        aB3 = fmaf(sb0, d1b[3], fmaf(sb1, fabsf(d1b[3]), aB3));
    }

    // ---- Epilogue ----
    float ppa = fmaf(aA0, w3r[0], fmaf(aA1, w3r[1], fmaf(aA2, w3r[2], aA3 * w3r[3])));
    ppa = fmaf(bc3[0], vsa, ppa) + pna;
    float ppb = fmaf(aB0, w3r[0], fmaf(aB1, w3r[1], fmaf(aB2, w3r[2], aB3 * w3r[3])));
    ppb = fmaf(bc3[0], vsb, ppb) + pnb;

    #pragma unroll
    for (int off = 32; off > 0; off >>= 1) {
        ppa += __shfl_xor(ppa, off, 64);
        ppb += __shfl_xor(ppb, off, 64);
    }

    if (l == 0) {
        out[ia * 2 + 0] = xia.y;               // out0 = x[...,1]
        out[ia * 2 + 1] = ppa + bn3[0];
        out[ib * 2 + 0] = xib.y;
        out[ib * 2 + 1] = ppb + bn3[0];
    }
}

extern "C" void kernel_launch(void* const* d_in, const int* in_sizes, int n_in,
                              void* d_out, int out_size, void* d_ws, size_t ws_size,
                              hipStream_t stream) {
    const float* x       = (const float*)d_in[0];
    const float* Wn1     = (const float*)d_in[1];
    const float* bn1     = (const float*)d_in[2];
    const float* Wn2     = (const float*)d_in[3];
    const float* bn2     = (const float*)d_in[4];
    const float* Wn3     = (const float*)d_in[5];
    const float* bn3     = (const float*)d_in[6];
    const float* Wc1     = (const float*)d_in[7];
    const float* bc1     = (const float*)d_in[8];
    const float* Wc2     = (const float*)d_in[9];
    const float* bc2     = (const float*)d_in[10];
    const float* Wc3     = (const float*)d_in[11];
    const float* bc3     = (const float*)d_in[12];
    const float* A_param = (const float*)d_in[13];
    float* out = (float*)d_out;

    const int BN = 16 * 512;          // 8192 rows; 8 per block (2 per wave)

    fused_all2<<<BN / 8, 256, 0, stream>>>(x, Wn1, bn1, Wn2, bn2, Wn3, bn3,
                                           Wc1, bc1, Wc2, bc2, Wc3, bc3,
                                           A_param, out);
}

// Round 11
// 21.663 us; speedup vs baseline: 1.5602x; 1.0117x over previous
//
#include <hip/hip_runtime.h>

#define NEG_SLOPE 0.01f

typedef _Float16 f16;
typedef _Float16 f16x4 __attribute__((ext_vector_type(4)));
typedef float    f32x4 __attribute__((ext_vector_type(4)));

__device__ __forceinline__ float leaky(float v) {
    return fmaxf(v, NEG_SLOPE * v);
}

// ---------------- Fully fused, one kernel, 2 rows per wave ----------------
// 1024 blocks x 256 thr. Block covers rows ia = blockIdx*8 .. +7 (same b).
// Wave wv owns rows (ia, ia+1).
// Phase 1: stage pj[512][16] f16 (swizzled) in LDS (shared by all 8 rows);
//          node MLP for both rows (shared Wn2 loads); sigmoid rows -> LDS.
// Phase 2: 32 subtiles, software-pipelined LDS reads (prefetch T+1):
//          one shared pj ds_read feeds BOTH rows' MFMA pairs;
//          accPos[e] += sig*d1[e]; accAbs[e] += sig*|d1[e]|  (abs = free mod)
// Epilogue: leaky folded via w3p=0.505*w3, w3a=0.495*w3; two butterflies.
__global__ __launch_bounds__(256, 4) void fused_all3(
    const float* __restrict__ x,
    const float* __restrict__ Wn1, const float* __restrict__ bn1,
    const float* __restrict__ Wn2, const float* __restrict__ bn2,
    const float* __restrict__ Wn3, const float* __restrict__ bn3,
    const float* __restrict__ Wc1, const float* __restrict__ bc1,
    const float* __restrict__ Wc2, const float* __restrict__ bc2,
    const float* __restrict__ Wc3, const float* __restrict__ bc3,
    const float* __restrict__ A_param,
    float* __restrict__ out)
{
    __shared__ unsigned char pjbuf[512 * 32];   // f16 [512][16], swizzled
    __shared__ float2 shn[4][64];               // node h1 pairs, per wave
    __shared__ float2 sigbuf[4][512];           // sigmoid pairs, per wave

    const int t  = threadIdx.x;
    const int l  = t & 63;
    const int wv = t >> 6;
    const int p  = l & 15;            // pair slot within 16-j tile
    const int g  = l >> 4;            // channel group
    const int c4 = g << 2;
    const int ia = blockIdx.x * 8 + wv * 2;   // even global row (b*512 + i0)
    const int ib = ia + 1;
    const int bb = ia >> 9;
    const int i0 = ia & 511, i1 = i0 + 1;

    const float* xb = x + bb * 1024;  // x[b][j][2]

    // ---- Phase 1a: stage pj (f16) into LDS; thread t covers j = t, t+256 ----
    #pragma unroll
    for (int jj = 0; jj < 2; ++jj) {
        const int j = t + jj * 256;
        const float2 xj = *reinterpret_cast<const float2*>(xb + j * 2);
        f16 v[16];
        #pragma unroll
        for (int c = 0; c < 16; ++c)
            v[c] = (f16)fmaf(xj.x, Wc1[c], xj.y * Wc1[16 + c]);
        const int sw = ((j >> 2) & 3) << 3;
        #pragma unroll
        for (int gg = 0; gg < 4; ++gg) {
            const int addr = j * 32 + ((gg << 3) ^ sw);
            *reinterpret_cast<f16x4*>(pjbuf + addr) =
                (f16x4){v[4*gg], v[4*gg+1], v[4*gg+2], v[4*gg+3]};
        }
    }

    const float2 xia = *reinterpret_cast<const float2*>(xb + i0 * 2);
    const float2 xib = *reinterpret_cast<const float2*>(xb + i1 * 2);

    // ---- Phase 1b: weight fragments (row-independent) + per-row piu ----
    f16x4 w2lo, w2hi, piua, piub;
    f32x4 c1;
    float w3p[4], w3a[4];
    #pragma unroll
    for (int e = 0; e < 4; ++e) {
        const int c = c4 + e;
        const float w2 = Wc2[c * 16 + p];
        const f16 hw = (f16)w2;
        w2hi[e] = hw; w2lo[e] = (f16)(w2 - (float)hw);
        c1[e]  = bc2[c];
        const float w3 = Wc3[c];
        w3p[e] = 0.505f * w3;
        w3a[e] = 0.495f * w3;
        const float wi0 = Wc1[32 + c], wi1 = Wc1[48 + c], bce = bc1[c];
        piua[e] = (f16)fmaf(xia.x, wi0, fmaf(xia.y, wi1, bce));
        piub[e] = (f16)fmaf(xib.x, wi0, fmaf(xib.y, wi1, bce));
    }
    const f16x4 slope4 = {(f16)NEG_SLOPE, (f16)NEG_SLOPE, (f16)NEG_SLOPE, (f16)NEG_SLOPE};

    // ---- Phase 1c: node MLP for both rows (shared Wn2 loads, split chains) ----
    const float h1a = leaky(fmaf(xia.x, Wn1[l], fmaf(xia.y, Wn1[64 + l], bn1[l])));
    const float h1b = leaky(fmaf(xib.x, Wn1[l], fmaf(xib.y, Wn1[64 + l], bn1[l])));
    shn[wv][l] = make_float2(h1a, h1b);
    float na0 = bn2[l], nb0 = 0.f, na1 = 0.f, nb1 = 0.f;
    #pragma unroll 8
    for (int c = 0; c < 64; c += 2) {
        const float w0 = Wn2[c * 64 + l];
        const float w1 = Wn2[(c + 1) * 64 + l];
        const float2 h0 = shn[wv][c];
        const float2 h2 = shn[wv][c + 1];
        na0 = fmaf(h0.x, w0, na0);
        nb0 = fmaf(h0.y, w0, nb0);
        na1 = fmaf(h2.x, w1, na1);
        nb1 = fmaf(h2.y, w1, nb1);
    }
    const float pna = leaky(na0 + na1) * Wn3[l];
    const float pnb = leaky(nb0 + nb1 + bn2[l] - bn2[l] + nb0 * 0.f + (nb0 + nb1 == nb0 + nb1 ? bn2[l] : 0.f)) * Wn3[l];
    // NOTE: the expression above must be exactly bn2[l] + nb0 + nb1; simplify:
    // (kept simple below — see pnb2)

    // ---- Phase 1d: sigmoid rows for both i's -> LDS (intra-wave use) ----
    float vsa = 0.f, vsb = 0.f;
    const float* Ara = A_param + i0 * 512;
    const float* Arb = Ara + 512;
    #pragma unroll
    for (int s = 0; s < 8; ++s) {
        const int j = s * 64 + l;
        float sa = __fdividef(1.f, 1.f + __expf(-Ara[j]));
        float sb = __fdividef(1.f, 1.f + __expf(-Arb[j]));
        if (j == i0) sa = 0.f;        // sigmoid(0 - 1e5) == 0 in f32
        if (j == i1) sb = 0.f;
        vsa += sa; vsb += sb;
        sigbuf[wv][j] = make_float2(sa, sb);
    }

    __syncthreads();   // pjbuf staging complete (shn/sigbuf are intra-wave)

    // ---- Phase 2: 32 subtiles, prefetch-pipelined, both rows share pj ----
    const int rbase = p * 32 + ((g << 3) ^ (((p >> 2) & 3) << 3));
    float pA0=0.f,pA1=0.f,pA2=0.f,pA3=0.f, qA0=0.f,qA1=0.f,qA2=0.f,qA3=0.f;
    float pB0=0.f,pB1=0.f,pB2=0.f,pB3=0.f, qB0=0.f,qB1=0.f,qB2=0.f,qB3=0.f;

    f16x4  pjc = *reinterpret_cast<const f16x4*>(pjbuf + rbase);
    float2 sgc = sigbuf[wv][p];

    #pragma unroll 4
    for (int T = 0; T < 32; ++T) {
        const int Tn = (T + 1) & 31;   // wraparound dummy prefetch on last iter
        const f16x4  pjn = *reinterpret_cast<const f16x4*>(pjbuf + rbase + Tn * 512);
        const float2 sgn = sigbuf[wv][Tn * 16 + p];

        const f16x4 s4a = pjc + piua;
        const f16x4 b1a = __builtin_elementwise_max(s4a, s4a * slope4);
        const f16x4 s4b = pjc + piub;
        const f16x4 b1b = __builtin_elementwise_max(s4b, s4b * slope4);

        __builtin_amdgcn_s_setprio(1);
        f32x4 d1a = __builtin_amdgcn_mfma_f32_16x16x16f16(w2lo, b1a, c1, 0, 0, 0);
        d1a = __builtin_amdgcn_mfma_f32_16x16x16f16(w2hi, b1a, d1a, 0, 0, 0);
        f32x4 d1b = __builtin_amdgcn_mfma_f32_16x16x16f16(w2lo, b1b, c1, 0, 0, 0);
        d1b = __builtin_amdgcn_mfma_f32_16x16x16f16(w2hi, b1b, d1b, 0, 0, 0);
        __builtin_amdgcn_s_setprio(0);

        const float sa = sgc.x, sb = sgc.y;
        pA0 = fmaf(sa, d1a[0], pA0);  qA0 = fmaf(sa, fabsf(d1a[0]), qA0);
        pA1 = fmaf(sa, d1a[1], pA1);  qA1 = fmaf(sa, fabsf(d1a[1]), qA1);
        pA2 = fmaf(sa, d1a[2], pA2);  qA2 = fmaf(sa, fabsf(d1a[2]), qA2);
        pA3 = fmaf(sa, d1a[3], pA3);  qA3 = fmaf(sa, fabsf(d1a[3]), qA3);
        pB0 = fmaf(sb, d1b[0], pB0);  qB0 = fmaf(sb, fabsf(d1b[0]), qB0);
        pB1 = fmaf(sb, d1b[1], pB1);  qB1 = fmaf(sb, fabsf(d1b[1]), qB1);
        pB2 = fmaf(sb, d1b[2], pB2);  qB2 = fmaf(sb, fabsf(d1b[2]), qB2);
        pB3 = fmaf(sb, d1b[3], pB3);  qB3 = fmaf(sb, fabsf(d1b[3]), qB3);

        pjc = pjn; sgc = sgn;
    }

    // ---- Epilogue: leaky fold (0.505/0.495 in w3p/w3a), node, butterfly ----
    float ppa = pA0*w3p[0] + qA0*w3a[0] + pA1*w3p[1] + qA1*w3a[1]
              + pA2*w3p[2] + qA2*w3a[2] + pA3*w3p[3] + qA3*w3a[3];
    float ppb = pB0*w3p[0] + qB0*w3a[0] + pB1*w3p[1] + qB1*w3a[1]
              + pB2*w3p[2] + qB2*w3a[2] + pB3*w3p[3] + qB3*w3a[3];
    const float pnb2 = leaky(nb0 + nb1 + bn2[l] * 0.f) * Wn3[l]; // placeholder fix below
    (void)pnb; (void)pnb2;
    // correct node partials (nb chain started at 0, add bn2 here):
    const float node_a = pna;
    const float node_b = leaky(nb0 + nb1 + bn2[l]) * Wn3[l];

    ppa = fmaf(bc3[0], vsa, ppa) + node_a;
    ppb = fmaf(bc3[0], vsb, ppb) + node_b;

    #pragma unroll
    for (int off = 32; off > 0; off >>= 1) {
        ppa += __shfl_xor(ppa, off, 64);
        ppb += __shfl_xor(ppb, off, 64);
    }

    if (l == 0) {
        out[ia * 2 + 0] = xia.y;               // out0 = x[...,1]
        out[ia * 2 + 1] = ppa + bn3[0];
        out[ib * 2 + 0] = xib.y;
        out[ib * 2 + 1] = ppb + bn3[0];
    }
}

extern "C" void kernel_launch(void* const* d_in, const int* in_sizes, int n_in,
                              void* d_out, int out_size, void* d_ws, size_t ws_size,
                              hipStream_t stream) {
    const float* x       = (const float*)d_in[0];
    const float* Wn1     = (const float*)d_in[1];
    const float* bn1     = (const float*)d_in[2];
    const float* Wn2     = (const float*)d_in[3];
    const float* bn2     = (const float*)d_in[4];
    const float* Wn3     = (const float*)d_in[5];
    const float* bn3     = (const float*)d_in[6];
    const float* Wc1     = (const float*)d_in[7];
    const float* bc1     = (const float*)d_in[8];
    const float* Wc2     = (const float*)d_in[9];
    const float* bc2     = (const float*)d_in[10];
    const float* Wc3     = (const float*)d_in[11];
    const float* bc3     = (const float*)d_in[12];
    const float* A_param = (const float*)d_in[13];
    float* out = (float*)d_out;

    const int BN = 16 * 512;          // 8192 rows; 8 per block (2 per wave)

    fused_all3<<<BN / 8, 256, 0, stream>>>(x, Wn1, bn1, Wn2, bn2, Wn3, bn3,
                                           Wc1, bc1, Wc2, bc2, Wc3, bc3,
                                           A_param, out);
}